// Round 4
// baseline (8794.460 us; speedup 1.0000x reference)
//
#include <hip/hip_runtime.h>
#include <stdint.h>

#define TLEN 1024
#define BATCH 64
#define DIMX 128
#define HID 512

typedef __attribute__((ext_vector_type(8))) short short8;
typedef __attribute__((ext_vector_type(4))) float f32x4;

// ---- workspace layout (bytes) ----
#define OFF_WT   0u           // Wt: [2048][640] bf16 = 2,621,440
#define OFF_XBF  2621440u     // xbf: [64][1024][128] bf16 = 16,777,216
#define OFF_HB   19398656u    // hb: [2][64][512] u32 (tagged bf16) = 262,144
#define OFF_FLG  19660800u    // subflags: [8 groups][64] u32 = 2,048
#define OFF_ACC  19662848u    // acc: 64
#define ZERO_LEN (262144u + 2048u + 64u)

__device__ __forceinline__ unsigned short f2bf(float f) {
  unsigned u = __float_as_uint(f);
  u += 0x7fffu + ((u >> 16) & 1u);
  return (unsigned short)(u >> 16);
}
__device__ __forceinline__ float sigm(float x) { return 1.0f / (1.0f + __expf(-x)); }
__device__ __forceinline__ float tanh_fast(float x) {
  float a = fabsf(x);
  float e = __expf(2.0f * a);
  float t = 1.0f - 2.0f / (e + 1.0f);
  return copysignf(t, x);
}
__device__ __forceinline__ unsigned long long aload64(const unsigned* p) {
  return __hip_atomic_load((const unsigned long long*)p, __ATOMIC_RELAXED,
                           __HIP_MEMORY_SCOPE_AGENT);
}
__device__ __forceinline__ unsigned aload32(const unsigned* p) {
  return __hip_atomic_load(p, __ATOMIC_RELAXED, __HIP_MEMORY_SCOPE_AGENT);
}

// ---- x fp32 -> bf16, coalesced ----
__global__ void k_convx(const float4* __restrict__ x4, ushort4* __restrict__ o4) {
  int i = blockIdx.x * 256 + threadIdx.x;
  float4 v = x4[i];
  ushort4 o;
  o.x = f2bf(v.x); o.y = f2bf(v.y); o.z = f2bf(v.z); o.w = f2bf(v.w);
  o4[i] = o;
}

// ---- build Wt[col 0..2047][k 0..639] bf16 = concat(Wx;Wh)^T (proven) ----
__global__ void k_tw(const float* __restrict__ Wx, const float* __restrict__ Wh,
                     unsigned short* __restrict__ Wt) {
  __shared__ float tile[32][65];
  int bk = blockIdx.x;
  int k0 = (bk / 64) * 64;
  int c0 = (bk % 64) * 32;
  int tid = threadIdx.x;
  const float* src = (k0 < 128) ? (Wx + (size_t)k0 * 2048)
                                : (Wh + (size_t)(k0 - 128) * 2048);
#pragma unroll
  for (int p = 0; p < 8; ++p) {
    int i = p * 256 + tid;
    int kk = i >> 5, cc = i & 31;
    tile[cc][kk] = src[(size_t)kk * 2048 + (c0 + cc)];
  }
  __syncthreads();
  int cc = tid >> 3, ch = tid & 7;
  unsigned short tmp[8];
#pragma unroll
  for (int j = 0; j < 8; ++j) tmp[j] = f2bf(tile[cc][ch * 8 + j]);
  uint4 o;
  o.x = (unsigned)tmp[0] | ((unsigned)tmp[1] << 16);
  o.y = (unsigned)tmp[2] | ((unsigned)tmp[3] << 16);
  o.z = (unsigned)tmp[4] | ((unsigned)tmp[5] << 16);
  o.w = (unsigned)tmp[6] | ((unsigned)tmp[7] << 16);
  *(uint4*)(Wt + (size_t)(c0 + cc) * 640 + k0 + ch * 8) = o;
}

// ---- recurrence: 128 WGs = 8 groups x 16 WGs(512thr). R2 dataflow + subflag
// notification (tiny spin footprint) + tagged-data verify as backstop. ----
__global__ __launch_bounds__(512, 1) void k_lstm(
    const unsigned short* __restrict__ xbf,   // [B][T][D] bf16
    const unsigned short* __restrict__ Wt,    // [4H][640] bf16 (B^T layout)
    const float* __restrict__ bias,           // [4H]
    const float* __restrict__ Wo,             // [H][2]
    unsigned* __restrict__ hb,                // [2][B][H] tagged u32
    unsigned* __restrict__ flags,             // [8][64] subflags
    float* __restrict__ out)                  // [B][T][2] logits via atomicAdd
{
  __shared__ float red[2][4][4][8][32];  // [buf][kw][gate][row][col]

  const int tid  = threadIdx.x;
  const int w    = tid >> 6;      // wave 0..7
  const int kw   = w & 3;         // K-split: K range kw*160..+159
  const int cg   = w >> 2;        // gate pair: gates 2cg, 2cg+1
  const int lane = tid & 63;
  const int q    = lane >> 4;
  const int m    = lane & 15;
  const int grp  = blockIdx.x & 7;   // group -> same XCD under %8 round-robin
  const int hj   = blockIdx.x >> 3;  // producer slice id 0..15 (cols hj*32..+31)
  const int g0   = grp * 8;

  // ---- pin weight slice in registers ----
  short8 Bf[5][4];
#pragma unroll
  for (int kk = 0; kk < 5; ++kk) {
#pragma unroll
    for (int j = 0; j < 4; ++j) {
      int gate = cg * 2 + (j >> 1);
      int col = gate * HID + hj * 32 + (j & 1) * 16 + m;
      int k = kw * 160 + kk * 32 + q * 8;
      Bf[kk][j] = *(const short8*)(Wt + (size_t)col * 640 + k);
    }
  }

  // gate-thread state: tid<256 owns (row=tid>>5, col=tid&31)
  const int row = tid >> 5;
  const int col = tid & 31;
  const int hcol = hj * 32 + col;
  float c_state = 0.0f;
  float b_i = 0, b_f = 0, b_g = 0, b_o = 0;
  float2 wo = {0.f, 0.f};
  if (tid < 256) {
    b_i = bias[0 * HID + hcol];
    b_f = bias[1 * HID + hcol];
    b_g = bias[2 * HID + hcol];
    b_o = bias[3 * HID + hcol];
    wo = ((const float2*)Wo)[hcol];
  }

  const int arow = (m < 8) ? m : 7;   // clamp pad rows
  const int ab = g0 + arow;

  // subflag need-mask: lane l <-> (producer p=l>>2, producer-wave sw=l&3)
  unsigned* gflag = flags + grp * 64;
  const unsigned long long needbits =
      (kw == 0) ? 0x000000000000000Full :
      (kw == 1) ? 0x0000000000FFFFF0ull :
      (kw == 2) ? 0x00000FFFFF000000ull : 0xFFFFF00000000000ull;
  const bool mine = (needbits >> lane) & 1ull;

#pragma unroll 1
  for (int t = 0; t < TLEN; ++t) {
    const unsigned* hin = hb + (size_t)(t & 1) * (BATCH * HID);

    // ---- spin on subflags of needed producers only (4 lines/group) ----
    {
      unsigned tgt = (unsigned)t;
      int guard = 0;
      for (;;) {
        unsigned f = mine ? aload32(gflag + lane) : 0xFFFFFFFFu;
        if (__ballot(mine && (f < tgt)) == 0ull || ++guard > (1 << 22)) break;
      }
    }

    // ---- A fragments: x plain loads, h tagged loads (verify, rare retry) ----
    short8 a[5];
    unsigned long long wb[5][4];
#pragma unroll
    for (int kk = 0; kk < 5; ++kk) {
      int k = kw * 160 + kk * 32 + q * 8;
      if (k < 128) {
        a[kk] = *(const short8*)(xbf + ((size_t)ab * TLEN + t) * DIMX + k);
      } else {
        const unsigned* p = hin + ab * HID + (k - 128);
#pragma unroll
        for (int j = 0; j < 4; ++j) wb[kk][j] = aload64(p + j * 2);
      }
    }
    {
      unsigned long long rep = (unsigned)t;
      rep |= rep << 32;
      const unsigned long long MSK = 0x0000FFFF0000FFFFull;
      int guard = 0;
      for (;;) {
        bool all = true;
#pragma unroll
        for (int kk = 0; kk < 5; ++kk) {
          int k = kw * 160 + kk * 32 + q * 8;
          if (k >= 128) {
            unsigned long long d = (wb[kk][0] ^ rep) | (wb[kk][1] ^ rep) |
                                   (wb[kk][2] ^ rep) | (wb[kk][3] ^ rep);
            if ((d & MSK) != 0ull) {
              all = false;
              const unsigned* p = hin + ab * HID + (k - 128);
#pragma unroll
              for (int j = 0; j < 4; ++j) wb[kk][j] = aload64(p + j * 2);
            }
          }
        }
        if (all || ++guard > (1 << 20)) break;
      }
#pragma unroll
      for (int kk = 0; kk < 5; ++kk) {
        int k = kw * 160 + kk * 32 + q * 8;
        if (k >= 128) {
          union { short8 s; unsigned u[4]; } r;
#pragma unroll
          for (int j = 0; j < 4; ++j) {
            unsigned lo = (unsigned)wb[kk][j], hi = (unsigned)(wb[kk][j] >> 32);
            r.u[j] = (lo >> 16) | (hi & 0xFFFF0000u);
          }
          a[kk] = r.s;
        }
      }
    }

    // ---- MFMA: z partials for this wave's K-slice, gate pair ----
    f32x4 z0 = {0,0,0,0}, z1 = {0,0,0,0}, z2 = {0,0,0,0}, z3 = {0,0,0,0};
#pragma unroll
    for (int kk = 0; kk < 5; ++kk) {
      z0 = __builtin_amdgcn_mfma_f32_16x16x32_bf16(a[kk], Bf[kk][0], z0, 0, 0, 0);
      z1 = __builtin_amdgcn_mfma_f32_16x16x32_bf16(a[kk], Bf[kk][1], z1, 0, 0, 0);
      z2 = __builtin_amdgcn_mfma_f32_16x16x32_bf16(a[kk], Bf[kk][2], z2, 0, 0, 0);
      z3 = __builtin_amdgcn_mfma_f32_16x16x32_bf16(a[kk], Bf[kk][3], z3, 0, 0, 0);
    }

    // ---- stage partials (valid rows in quads 0,1), double-buffered ----
    const int buf = t & 1;
    if (q < 2) {
#pragma unroll
      for (int r = 0; r < 4; ++r) {
        int rw = q * 4 + r;
        red[buf][kw][cg * 2 + 0][rw][0 * 16 + m] = z0[r];
        red[buf][kw][cg * 2 + 0][rw][1 * 16 + m] = z1[r];
        red[buf][kw][cg * 2 + 1][rw][0 * 16 + m] = z2[r];
        red[buf][kw][cg * 2 + 1][rw][1 * 16 + m] = z3[r];
      }
    }
    __syncthreads();   // the only rendezvous per step

    // ---- gates + state + tagged h store + per-wave flag + logit duty ----
    if (tid < 256) {
      float zi = b_i + red[buf][0][0][row][col] + red[buf][1][0][row][col]
                     + red[buf][2][0][row][col] + red[buf][3][0][row][col];
      float zf = b_f + red[buf][0][1][row][col] + red[buf][1][1][row][col]
                     + red[buf][2][1][row][col] + red[buf][3][1][row][col];
      float zg = b_g + red[buf][0][2][row][col] + red[buf][1][2][row][col]
                     + red[buf][2][2][row][col] + red[buf][3][2][row][col];
      float zo = b_o + red[buf][0][3][row][col] + red[buf][1][3][row][col]
                     + red[buf][2][3][row][col] + red[buf][3][3][row][col];
      float ig = sigm(zi), fg = sigm(zf), gg = tanh_fast(zg), og = sigm(zo);
      c_state = fg * c_state + ig * gg;
      float hval = og * tanh_fast(c_state);

      unsigned hword = ((unsigned)f2bf(hval) << 16) | (unsigned)((t + 1) & 0xFFFF);
      __hip_atomic_store(hb + (size_t)((t + 1) & 1) * (BATCH * HID) +
                             (size_t)(g0 + row) * HID + hcol,
                         hword, __ATOMIC_RELAXED, __HIP_MEMORY_SCOPE_AGENT);

      // retire this wave's h stores, then publish subflag (hint; tags backstop)
      __builtin_amdgcn_s_waitcnt(0);
      if ((tid & 63) == 0)
        __hip_atomic_store(gflag + hj * 4 + w, (unsigned)(t + 1),
                           __ATOMIC_RELAXED, __HIP_MEMORY_SCOPE_AGENT);

      // logit partials AFTER flag (their ack latency off critical path)
      float p0 = hval * wo.x, p1 = hval * wo.y;
      p0 += __shfl_xor(p0, 16); p1 += __shfl_xor(p1, 16);
      p0 += __shfl_xor(p0, 8);  p1 += __shfl_xor(p1, 8);
      p0 += __shfl_xor(p0, 4);  p1 += __shfl_xor(p1, 4);
      p0 += __shfl_xor(p0, 2);  p1 += __shfl_xor(p1, 2);
      p0 += __shfl_xor(p0, 1);  p1 += __shfl_xor(p1, 1);
      if (col == 0) {
        float* po = out + ((size_t)(g0 + row) * TLEN + t) * 2;
        atomicAdd(po + 0, p0);
        atomicAdd(po + 1, p1);
      }
    }
  }
}

// ---- logits -> softmax probs + NLL ----
__global__ void k_out2(float* __restrict__ out, const float* __restrict__ bo,
                       const int* __restrict__ labels, float* __restrict__ acc) {
  __shared__ float sred[4];
  int i = blockIdx.x * 256 + threadIdx.x;   // 0..65535 = b*T + t
  float l0 = out[(size_t)i * 2 + 0] + bo[0];
  float l1 = out[(size_t)i * 2 + 1] + bo[1];
  float mx = fmaxf(l0, l1);
  float e0 = __expf(l0 - mx), e1 = __expf(l1 - mx);
  float s = e0 + e1, inv = 1.0f / s;
  out[(size_t)i * 2 + 0] = e0 * inv;
  out[(size_t)i * 2 + 1] = e1 * inv;
  int lab = labels[i];
  float nll = __logf(s) - ((lab ? l1 : l0) - mx);
#pragma unroll
  for (int off = 32; off >= 1; off >>= 1) nll += __shfl_xor(nll, off);
  if ((threadIdx.x & 63) == 0) sred[threadIdx.x >> 6] = nll;
  __syncthreads();
  if (threadIdx.x == 0)
    atomicAdd(acc, sred[0] + sred[1] + sred[2] + sred[3]);
}

__global__ void k_fin(const float* __restrict__ acc, float* __restrict__ out) {
  out[BATCH * TLEN * 2] = acc[0] * (1.0f / (float)(BATCH * TLEN));
}

extern "C" void kernel_launch(void* const* d_in, const int* in_sizes, int n_in,
                              void* d_out, int out_size, void* d_ws, size_t ws_size,
                              hipStream_t stream) {
  const float* x      = (const float*)d_in[0];
  const int*   labels = (const int*)d_in[1];
  const float* Wx     = (const float*)d_in[2];
  const float* Wh     = (const float*)d_in[3];
  const float* b      = (const float*)d_in[4];
  const float* Wo     = (const float*)d_in[5];
  const float* bo     = (const float*)d_in[6];
  float* out = (float*)d_out;
  char* ws = (char*)d_ws;

  unsigned short* Wt    = (unsigned short*)(ws + OFF_WT);
  unsigned short* xbf   = (unsigned short*)(ws + OFF_XBF);
  unsigned*       hb    = (unsigned*)(ws + OFF_HB);
  unsigned*       flags = (unsigned*)(ws + OFF_FLG);
  float*          acc   = (float*)(ws + OFF_ACC);

  // hb zero => h_0 = 0 tag 0; flags zero => step-0 pass; acc zero; out zero
  hipMemsetAsync(ws + OFF_HB, 0, ZERO_LEN, stream);
  hipMemsetAsync(d_out, 0, (size_t)BATCH * TLEN * 2 * sizeof(float), stream);
  k_convx<<<8192, 256, 0, stream>>>((const float4*)x, (ushort4*)xbf);
  k_tw<<<640, 256, 0, stream>>>(Wx, Wh, Wt);
  k_lstm<<<128, 512, 0, stream>>>(xbf, Wt, b, Wo, hb, flags, out);
  k_out2<<<256, 256, 0, stream>>>(out, bo, labels, acc);
  k_fin<<<1, 1, 0, stream>>>(acc, out);
}

// Round 5
// 7033.103 us; speedup vs baseline: 1.2504x; 1.2504x over previous
//
#include <hip/hip_runtime.h>
#include <stdint.h>

#define TLEN 1024
#define BATCH 64
#define DIMX 128
#define HID 512

typedef __attribute__((ext_vector_type(8))) short short8;
typedef __attribute__((ext_vector_type(4))) float f32x4;

// ---- workspace layout (bytes) ----
#define OFF_WT   0u           // Wt: [2048][640] bf16 = 2,621,440
#define OFF_XBF  2621440u     // xbf: [64][1024][128] bf16 = 16,777,216
#define OFF_HB   19398656u    // hb: [2][64][512] u32 (tagged bf16) = 262,144
#define OFF_ACC  19660800u    // acc: 64
#define ZERO_LEN (262144u + 64u)

__device__ __forceinline__ unsigned short f2bf(float f) {
  unsigned u = __float_as_uint(f);
  u += 0x7fffu + ((u >> 16) & 1u);
  return (unsigned short)(u >> 16);
}
__device__ __forceinline__ float sigm(float x) { return 1.0f / (1.0f + __expf(-x)); }
__device__ __forceinline__ float tanh_fast(float x) {
  float a = fabsf(x);
  float e = __expf(2.0f * a);
  float t = 1.0f - 2.0f / (e + 1.0f);
  return copysignf(t, x);
}
__device__ __forceinline__ unsigned long long aload64(const unsigned* p) {
  return __hip_atomic_load((const unsigned long long*)p, __ATOMIC_RELAXED,
                           __HIP_MEMORY_SCOPE_AGENT);
}

// ---- x fp32 -> bf16, coalesced ----
__global__ void k_convx(const float4* __restrict__ x4, ushort4* __restrict__ o4) {
  int i = blockIdx.x * 256 + threadIdx.x;
  float4 v = x4[i];
  ushort4 o;
  o.x = f2bf(v.x); o.y = f2bf(v.y); o.z = f2bf(v.z); o.w = f2bf(v.w);
  o4[i] = o;
}

// ---- build Wt[col 0..2047][k 0..639] bf16 = concat(Wx;Wh)^T (proven) ----
__global__ void k_tw(const float* __restrict__ Wx, const float* __restrict__ Wh,
                     unsigned short* __restrict__ Wt) {
  __shared__ float tile[32][65];
  int bk = blockIdx.x;
  int k0 = (bk / 64) * 64;
  int c0 = (bk % 64) * 32;
  int tid = threadIdx.x;
  const float* src = (k0 < 128) ? (Wx + (size_t)k0 * 2048)
                                : (Wh + (size_t)(k0 - 128) * 2048);
#pragma unroll
  for (int p = 0; p < 8; ++p) {
    int i = p * 256 + tid;
    int kk = i >> 5, cc = i & 31;
    tile[cc][kk] = src[(size_t)kk * 2048 + (c0 + cc)];
  }
  __syncthreads();
  int cc = tid >> 3, ch = tid & 7;
  unsigned short tmp[8];
#pragma unroll
  for (int j = 0; j < 8; ++j) tmp[j] = f2bf(tile[cc][ch * 8 + j]);
  uint4 o;
  o.x = (unsigned)tmp[0] | ((unsigned)tmp[1] << 16);
  o.y = (unsigned)tmp[2] | ((unsigned)tmp[3] << 16);
  o.z = (unsigned)tmp[4] | ((unsigned)tmp[5] << 16);
  o.w = (unsigned)tmp[6] | ((unsigned)tmp[7] << 16);
  *(uint4*)(Wt + (size_t)(c0 + cc) * 640 + k0 + ch * 8) = o;
}

// ---- recurrence: 64 WGs = 4 groups(16 rows) x 16 WGs(512thr = 8 waves) ----
// R2 tagged-dataflow mechanism; full 16-row MFMA tiles; s_sleep poll backoff.
__global__ __launch_bounds__(512, 1) void k_lstm(
    const unsigned short* __restrict__ xbf,   // [B][T][D] bf16
    const unsigned short* __restrict__ Wt,    // [4H][640] bf16 (B^T layout)
    const float* __restrict__ bias,           // [4H]
    const float* __restrict__ Wo,             // [H][2]
    unsigned* __restrict__ hb,                // [2][B][H] tagged u32
    float* __restrict__ out)                  // [B][T][2] logits via atomicAdd
{
  __shared__ float red[2][4][4][16][34];  // [buf][kw][gate][row][col(+pad)]

  const int tid  = threadIdx.x;
  const int w    = tid >> 6;      // wave 0..7
  const int kw   = w & 3;         // K-split: K range kw*160..+159
  const int cg   = w >> 2;        // gate pair: gates 2cg, 2cg+1
  const int lane = tid & 63;
  const int q    = lane >> 4;
  const int m    = lane & 15;
  const int grp  = blockIdx.x & 3;   // group (16 batch rows)
  const int hj   = blockIdx.x >> 2;  // producer slice 0..15 (cols hj*32..+31)
  const int g0   = grp * 16;

  // ---- pin weight slice in registers: 20 frags = 80 VGPRs ----
  short8 Bf[5][4];
#pragma unroll
  for (int kk = 0; kk < 5; ++kk) {
#pragma unroll
    for (int j = 0; j < 4; ++j) {
      int gate = cg * 2 + (j >> 1);
      int col = gate * HID + hj * 32 + (j & 1) * 16 + m;
      int k = kw * 160 + kk * 32 + q * 8;
      Bf[kk][j] = *(const short8*)(Wt + (size_t)col * 640 + k);
    }
  }

  // gate-thread mapping: all 512 threads own one (row, col) output
  const int row  = tid >> 5;     // 0..15
  const int col  = tid & 31;     // 0..31
  const int hcol = hj * 32 + col;
  float c_state = 0.0f;
  const float b_i = bias[0 * HID + hcol];
  const float b_f = bias[1 * HID + hcol];
  const float b_g = bias[2 * HID + hcol];
  const float b_o = bias[3 * HID + hcol];
  const float2 wo = ((const float2*)Wo)[hcol];

  const int ab = g0 + m;   // A-fragment batch row (all 16 valid)

#pragma unroll 1
  for (int t = 0; t < TLEN; ++t) {
    const unsigned* hin = hb + (size_t)(t & 1) * (BATCH * HID);

    // ---- A fragments: x plain loads, h tagged loads (detect==data) ----
    short8 a[5];
    unsigned long long wb[5][4];
#pragma unroll
    for (int kk = 0; kk < 5; ++kk) {
      int k = kw * 160 + kk * 32 + q * 8;
      if (k < 128) {
        a[kk] = *(const short8*)(xbf + ((size_t)ab * TLEN + t) * DIMX + k);
      } else {
        const unsigned* p = hin + ab * HID + (k - 128);
#pragma unroll
        for (int j = 0; j < 4; ++j) wb[kk][j] = aload64(p + j * 2);
      }
    }
    {
      unsigned long long rep = (unsigned)t;
      rep |= rep << 32;
      const unsigned long long MSK = 0x0000FFFF0000FFFFull;
      int guard = 0;
      for (;;) {
        bool all = true;
#pragma unroll
        for (int kk = 0; kk < 5; ++kk) {
          int k = kw * 160 + kk * 32 + q * 8;
          if (k >= 128) {
            unsigned long long d = (wb[kk][0] ^ rep) | (wb[kk][1] ^ rep) |
                                   (wb[kk][2] ^ rep) | (wb[kk][3] ^ rep);
            if ((d & MSK) != 0ull) {
              all = false;
              const unsigned* p = hin + ab * HID + (k - 128);
#pragma unroll
              for (int j = 0; j < 4; ++j) wb[kk][j] = aload64(p + j * 2);
            }
          }
        }
        if (all || ++guard > (1 << 20)) break;
        __builtin_amdgcn_s_sleep(1);   // ~64 cyc backoff: cap sweep rate
      }
#pragma unroll
      for (int kk = 0; kk < 5; ++kk) {
        int k = kw * 160 + kk * 32 + q * 8;
        if (k >= 128) {
          union { short8 s; unsigned u[4]; } r;
#pragma unroll
          for (int j = 0; j < 4; ++j) {
            unsigned lo = (unsigned)wb[kk][j], hi = (unsigned)(wb[kk][j] >> 32);
            r.u[j] = (lo >> 16) | (hi & 0xFFFF0000u);
          }
          a[kk] = r.s;
        }
      }
    }

    // ---- MFMA: z partials for this wave's K-slice, gate pair ----
    f32x4 z0 = {0,0,0,0}, z1 = {0,0,0,0}, z2 = {0,0,0,0}, z3 = {0,0,0,0};
#pragma unroll
    for (int kk = 0; kk < 5; ++kk) {
      z0 = __builtin_amdgcn_mfma_f32_16x16x32_bf16(a[kk], Bf[kk][0], z0, 0, 0, 0);
      z1 = __builtin_amdgcn_mfma_f32_16x16x32_bf16(a[kk], Bf[kk][1], z1, 0, 0, 0);
      z2 = __builtin_amdgcn_mfma_f32_16x16x32_bf16(a[kk], Bf[kk][2], z2, 0, 0, 0);
      z3 = __builtin_amdgcn_mfma_f32_16x16x32_bf16(a[kk], Bf[kk][3], z3, 0, 0, 0);
    }

    // ---- stage partials (all 16 rows valid), double-buffered ----
    const int buf = t & 1;
#pragma unroll
    for (int r = 0; r < 4; ++r) {
      int rw = q * 4 + r;
      red[buf][kw][cg * 2 + 0][rw][0 + m]  = z0[r];
      red[buf][kw][cg * 2 + 0][rw][16 + m] = z1[r];
      red[buf][kw][cg * 2 + 1][rw][0 + m]  = z2[r];
      red[buf][kw][cg * 2 + 1][rw][16 + m] = z3[r];
    }
    __syncthreads();   // the only rendezvous per step

    // ---- gates + state + tagged h store + logit duty (all threads) ----
    {
      float zi = b_i + red[buf][0][0][row][col] + red[buf][1][0][row][col]
                     + red[buf][2][0][row][col] + red[buf][3][0][row][col];
      float zf = b_f + red[buf][0][1][row][col] + red[buf][1][1][row][col]
                     + red[buf][2][1][row][col] + red[buf][3][1][row][col];
      float zg = b_g + red[buf][0][2][row][col] + red[buf][1][2][row][col]
                     + red[buf][2][2][row][col] + red[buf][3][2][row][col];
      float zo = b_o + red[buf][0][3][row][col] + red[buf][1][3][row][col]
                     + red[buf][2][3][row][col] + red[buf][3][3][row][col];
      float ig = sigm(zi), fg = sigm(zf), gg = tanh_fast(zg), og = sigm(zo);
      c_state = fg * c_state + ig * gg;
      float hval = og * tanh_fast(c_state);

      unsigned hword = ((unsigned)f2bf(hval) << 16) | (unsigned)((t + 1) & 0xFFFF);
      __hip_atomic_store(hb + (size_t)((t + 1) & 1) * (BATCH * HID) +
                             (size_t)(g0 + row) * HID + hcol,
                         hword, __ATOMIC_RELAXED, __HIP_MEMORY_SCOPE_AGENT);

      // logit partials AFTER h store (ack latency off critical path)
      float p0 = hval * wo.x, p1 = hval * wo.y;
      p0 += __shfl_xor(p0, 1);  p1 += __shfl_xor(p1, 1);
      p0 += __shfl_xor(p0, 2);  p1 += __shfl_xor(p1, 2);
      p0 += __shfl_xor(p0, 4);  p1 += __shfl_xor(p1, 4);
      p0 += __shfl_xor(p0, 8);  p1 += __shfl_xor(p1, 8);
      p0 += __shfl_xor(p0, 16); p1 += __shfl_xor(p1, 16);
      if ((lane & 31) == 0) {
        float* po = out + ((size_t)(g0 + row) * TLEN + t) * 2;
        atomicAdd(po + 0, p0);
        atomicAdd(po + 1, p1);
      }
    }
  }
}

// ---- logits -> softmax probs + NLL ----
__global__ void k_out2(float* __restrict__ out, const float* __restrict__ bo,
                       const int* __restrict__ labels, float* __restrict__ acc) {
  __shared__ float sred[4];
  int i = blockIdx.x * 256 + threadIdx.x;   // 0..65535 = b*T + t
  float l0 = out[(size_t)i * 2 + 0] + bo[0];
  float l1 = out[(size_t)i * 2 + 1] + bo[1];
  float mx = fmaxf(l0, l1);
  float e0 = __expf(l0 - mx), e1 = __expf(l1 - mx);
  float s = e0 + e1, inv = 1.0f / s;
  out[(size_t)i * 2 + 0] = e0 * inv;
  out[(size_t)i * 2 + 1] = e1 * inv;
  int lab = labels[i];
  float nll = __logf(s) - ((lab ? l1 : l0) - mx);
#pragma unroll
  for (int off = 32; off >= 1; off >>= 1) nll += __shfl_xor(nll, off);
  if ((threadIdx.x & 63) == 0) sred[threadIdx.x >> 6] = nll;
  __syncthreads();
  if (threadIdx.x == 0)
    atomicAdd(acc, sred[0] + sred[1] + sred[2] + sred[3]);
}

__global__ void k_fin(const float* __restrict__ acc, float* __restrict__ out) {
  out[BATCH * TLEN * 2] = acc[0] * (1.0f / (float)(BATCH * TLEN));
}

extern "C" void kernel_launch(void* const* d_in, const int* in_sizes, int n_in,
                              void* d_out, int out_size, void* d_ws, size_t ws_size,
                              hipStream_t stream) {
  const float* x      = (const float*)d_in[0];
  const int*   labels = (const int*)d_in[1];
  const float* Wx     = (const float*)d_in[2];
  const float* Wh     = (const float*)d_in[3];
  const float* b      = (const float*)d_in[4];
  const float* Wo     = (const float*)d_in[5];
  const float* bo     = (const float*)d_in[6];
  float* out = (float*)d_out;
  char* ws = (char*)d_ws;

  unsigned short* Wt  = (unsigned short*)(ws + OFF_WT);
  unsigned short* xbf = (unsigned short*)(ws + OFF_XBF);
  unsigned*       hb  = (unsigned*)(ws + OFF_HB);
  float*          acc = (float*)(ws + OFF_ACC);

  // hb zero => h_0 = 0 with tag 0 (self-validating); acc zero; out zero
  hipMemsetAsync(ws + OFF_HB, 0, ZERO_LEN, stream);
  hipMemsetAsync(d_out, 0, (size_t)BATCH * TLEN * 2 * sizeof(float), stream);
  k_convx<<<8192, 256, 0, stream>>>((const float4*)x, (ushort4*)xbf);
  k_tw<<<640, 256, 0, stream>>>(Wx, Wh, Wt);
  k_lstm<<<64, 512, 0, stream>>>(xbf, Wt, b, Wo, hb, out);
  k_out2<<<256, 256, 0, stream>>>(out, bo, labels, acc);
  k_fin<<<1, 1, 0, stream>>>(acc, out);
}

// Round 6
// 3300.331 us; speedup vs baseline: 2.6647x; 2.1310x over previous
//
#include <hip/hip_runtime.h>
#include <stdint.h>

#define TLEN 1024
#define BATCH 64
#define DIMX 128
#define HID 512

typedef __attribute__((ext_vector_type(8))) short short8;
typedef __attribute__((ext_vector_type(4))) float f32x4;
typedef __attribute__((ext_vector_type(4))) unsigned u32x4;

// ---- workspace layout (bytes) ----
#define OFF_WT   0u           // Wt: [2048][640] bf16 = 2,621,440
#define OFF_XBF  2621440u     // xbf: [64][1024][128] bf16 = 16,777,216
#define OFF_HB   19398656u    // hb: [2][64][512] u32 (tagged bf16) = 262,144
#define OFF_ACC  19660800u    // acc: 64
#define ZERO_LEN (262144u + 64u)

__device__ __forceinline__ unsigned short f2bf(float f) {
  unsigned u = __float_as_uint(f);
  u += 0x7fffu + ((u >> 16) & 1u);
  return (unsigned short)(u >> 16);
}
__device__ __forceinline__ float sigm(float x) { return 1.0f / (1.0f + __expf(-x)); }
__device__ __forceinline__ float tanh_fast(float x) {
  float a = fabsf(x);
  float e = __expf(2.0f * a);
  float t = 1.0f - 2.0f / (e + 1.0f);
  return copysignf(t, x);
}

// ---- x fp32 -> bf16, coalesced ----
__global__ void k_convx(const float4* __restrict__ x4, ushort4* __restrict__ o4) {
  int i = blockIdx.x * 256 + threadIdx.x;
  float4 v = x4[i];
  ushort4 o;
  o.x = f2bf(v.x); o.y = f2bf(v.y); o.z = f2bf(v.z); o.w = f2bf(v.w);
  o4[i] = o;
}

// ---- build Wt[col 0..2047][k 0..639] bf16 = concat(Wx;Wh)^T (proven) ----
__global__ void k_tw(const float* __restrict__ Wx, const float* __restrict__ Wh,
                     unsigned short* __restrict__ Wt) {
  __shared__ float tile[32][65];
  int bk = blockIdx.x;
  int k0 = (bk / 64) * 64;
  int c0 = (bk % 64) * 32;
  int tid = threadIdx.x;
  const float* src = (k0 < 128) ? (Wx + (size_t)k0 * 2048)
                                : (Wh + (size_t)(k0 - 128) * 2048);
#pragma unroll
  for (int p = 0; p < 8; ++p) {
    int i = p * 256 + tid;
    int kk = i >> 5, cc = i & 31;
    tile[cc][kk] = src[(size_t)kk * 2048 + (c0 + cc)];
  }
  __syncthreads();
  int cc = tid >> 3, ch = tid & 7;
  unsigned short tmp[8];
#pragma unroll
  for (int j = 0; j < 8; ++j) tmp[j] = f2bf(tile[cc][ch * 8 + j]);
  uint4 o;
  o.x = (unsigned)tmp[0] | ((unsigned)tmp[1] << 16);
  o.y = (unsigned)tmp[2] | ((unsigned)tmp[3] << 16);
  o.z = (unsigned)tmp[4] | ((unsigned)tmp[5] << 16);
  o.w = (unsigned)tmp[6] | ((unsigned)tmp[7] << 16);
  *(uint4*)(Wt + (size_t)(c0 + cc) * 640 + k0 + ch * 8) = o;
}

// ---- recurrence: 128 WGs = 8 groups(8 rows) x 16 WGs(512thr = 8 waves) ----
// R2 structure; balanced K-split; batched dwordx4 sc0sc1 bypass polls.
__global__ __launch_bounds__(512, 1) void k_lstm(
    const unsigned short* __restrict__ xbf,   // [B][T][D] bf16
    const unsigned short* __restrict__ Wt,    // [4H][640] bf16 (B^T layout)
    const float* __restrict__ bias,           // [4H]
    const float* __restrict__ Wo,             // [H][2]
    unsigned* __restrict__ hb,                // [2][B][H] tagged u32
    float* __restrict__ out)                  // [B][T][2] logits via atomicAdd
{
  __shared__ float red[2][4][4][8][32];  // [buf][kw][gate][row][col]

  const int tid  = threadIdx.x;
  const int w    = tid >> 6;      // wave 0..7
  const int kw   = w & 3;         // K-split: x chunk kw, h window kw*128..+127
  const int cg   = w >> 2;        // gate pair: gates 2cg, 2cg+1
  const int lane = tid & 63;
  const int q    = lane >> 4;
  const int m    = lane & 15;
  const int grp  = blockIdx.x & 7;
  const int hj   = blockIdx.x >> 3;  // producer slice 0..15 (cols hj*32..+31)
  const int g0   = grp * 8;

  // ---- pin weight slice in registers (balanced-K mapping) ----
  short8 Bf[5][4];
#pragma unroll
  for (int cc = 0; cc < 5; ++cc) {
#pragma unroll
    for (int j = 0; j < 4; ++j) {
      int gate = cg * 2 + (j >> 1);
      int col = gate * HID + hj * 32 + (j & 1) * 16 + m;
      int k = (cc == 0) ? (kw * 32 + q * 8)
                        : (128 + kw * 128 + (cc - 1) * 32 + q * 8);
      Bf[cc][j] = *(const short8*)(Wt + (size_t)col * 640 + k);
    }
  }

  // gate-thread state: tid<256 owns (row=tid>>5, col=tid&31)
  const int row = tid >> 5;
  const int col = tid & 31;
  const int hcol = hj * 32 + col;
  float c_state = 0.0f;
  float b_i = 0, b_f = 0, b_g = 0, b_o = 0;
  float2 wo = {0.f, 0.f};
  if (tid < 256) {
    b_i = bias[0 * HID + hcol];
    b_f = bias[1 * HID + hcol];
    b_g = bias[2 * HID + hcol];
    b_o = bias[3 * HID + hcol];
    wo = ((const float2*)Wo)[hcol];
  }

  const int arow = (m < 8) ? m : 7;   // clamp pad rows (coalesced dup = free)
  const int ab = g0 + arow;

#pragma unroll 1
  for (int t = 0; t < TLEN; ++t) {
    const unsigned* hin = hb + (size_t)(t & 1) * (BATCH * HID);

    // ---- x chunk (plain cached load) ----
    short8 a0 = *(const short8*)(xbf + ((size_t)ab * TLEN + t) * DIMX +
                                 kw * 32 + q * 8);

    // ---- h chunks: batched bypass poll, detect==data ----
    const unsigned* pb = hin + (size_t)ab * HID + kw * 128 + q * 8;
    u32x4 r0, r1, r2, r3, r4, r5, r6, r7;
    {
      const unsigned tg = (unsigned)t & 0xFFFFu;
      int guard = 0;
      for (;;) {
        asm volatile(
            "global_load_dwordx4 %0, %8, off sc0 sc1\n\t"
            "global_load_dwordx4 %1, %8, off offset:16 sc0 sc1\n\t"
            "global_load_dwordx4 %2, %8, off offset:128 sc0 sc1\n\t"
            "global_load_dwordx4 %3, %8, off offset:144 sc0 sc1\n\t"
            "global_load_dwordx4 %4, %8, off offset:256 sc0 sc1\n\t"
            "global_load_dwordx4 %5, %8, off offset:272 sc0 sc1\n\t"
            "global_load_dwordx4 %6, %8, off offset:384 sc0 sc1\n\t"
            "global_load_dwordx4 %7, %8, off offset:400 sc0 sc1\n\t"
            "s_waitcnt vmcnt(0)"
            : "=v"(r0), "=v"(r1), "=v"(r2), "=v"(r3),
              "=v"(r4), "=v"(r5), "=v"(r6), "=v"(r7)
            : "v"(pb)
            : "memory");
        unsigned d = (r0[0] ^ tg) | (r0[1] ^ tg) | (r0[2] ^ tg) | (r0[3] ^ tg);
        d |= (r1[0] ^ tg) | (r1[1] ^ tg) | (r1[2] ^ tg) | (r1[3] ^ tg);
        d |= (r2[0] ^ tg) | (r2[1] ^ tg) | (r2[2] ^ tg) | (r2[3] ^ tg);
        d |= (r3[0] ^ tg) | (r3[1] ^ tg) | (r3[2] ^ tg) | (r3[3] ^ tg);
        d |= (r4[0] ^ tg) | (r4[1] ^ tg) | (r4[2] ^ tg) | (r4[3] ^ tg);
        d |= (r5[0] ^ tg) | (r5[1] ^ tg) | (r5[2] ^ tg) | (r5[3] ^ tg);
        d |= (r6[0] ^ tg) | (r6[1] ^ tg) | (r6[2] ^ tg) | (r6[3] ^ tg);
        d |= (r7[0] ^ tg) | (r7[1] ^ tg) | (r7[2] ^ tg) | (r7[3] ^ tg);
        bool bad = (d & 0xFFFFu) != 0u;
        if (__ballot(bad) == 0ull || ++guard > (1 << 20)) break;
      }
    }

    // ---- pack tagged words -> bf16 A fragments ----
    short8 a[5];
    a[0] = a0;
    {
      union { short8 s; unsigned u[4]; } pk;
#define PACK(dst, RA, RB)                                            \
      pk.u[0] = (RA[0] >> 16) | (RA[1] & 0xFFFF0000u);               \
      pk.u[1] = (RA[2] >> 16) | (RA[3] & 0xFFFF0000u);               \
      pk.u[2] = (RB[0] >> 16) | (RB[1] & 0xFFFF0000u);               \
      pk.u[3] = (RB[2] >> 16) | (RB[3] & 0xFFFF0000u);               \
      dst = pk.s;
      PACK(a[1], r0, r1)
      PACK(a[2], r2, r3)
      PACK(a[3], r4, r5)
      PACK(a[4], r6, r7)
#undef PACK
    }

    // ---- MFMA: z partials for this wave's K-slice, gate pair ----
    f32x4 z0 = {0,0,0,0}, z1 = {0,0,0,0}, z2 = {0,0,0,0}, z3 = {0,0,0,0};
#pragma unroll
    for (int cc = 0; cc < 5; ++cc) {
      z0 = __builtin_amdgcn_mfma_f32_16x16x32_bf16(a[cc], Bf[cc][0], z0, 0, 0, 0);
      z1 = __builtin_amdgcn_mfma_f32_16x16x32_bf16(a[cc], Bf[cc][1], z1, 0, 0, 0);
      z2 = __builtin_amdgcn_mfma_f32_16x16x32_bf16(a[cc], Bf[cc][2], z2, 0, 0, 0);
      z3 = __builtin_amdgcn_mfma_f32_16x16x32_bf16(a[cc], Bf[cc][3], z3, 0, 0, 0);
    }

    // ---- stage partials (valid rows in quads 0,1), double-buffered ----
    const int buf = t & 1;
    if (q < 2) {
#pragma unroll
      for (int r = 0; r < 4; ++r) {
        int rw = q * 4 + r;
        red[buf][kw][cg * 2 + 0][rw][0 * 16 + m] = z0[r];
        red[buf][kw][cg * 2 + 0][rw][1 * 16 + m] = z1[r];
        red[buf][kw][cg * 2 + 1][rw][0 * 16 + m] = z2[r];
        red[buf][kw][cg * 2 + 1][rw][1 * 16 + m] = z3[r];
      }
    }
    __syncthreads();   // the only rendezvous per step

    // ---- gates + state + tagged h store + logit duty ----
    if (tid < 256) {
      float zi = b_i + red[buf][0][0][row][col] + red[buf][1][0][row][col]
                     + red[buf][2][0][row][col] + red[buf][3][0][row][col];
      float zf = b_f + red[buf][0][1][row][col] + red[buf][1][1][row][col]
                     + red[buf][2][1][row][col] + red[buf][3][1][row][col];
      float zg = b_g + red[buf][0][2][row][col] + red[buf][1][2][row][col]
                     + red[buf][2][2][row][col] + red[buf][3][2][row][col];
      float zo = b_o + red[buf][0][3][row][col] + red[buf][1][3][row][col]
                     + red[buf][2][3][row][col] + red[buf][3][3][row][col];
      float ig = sigm(zi), fg = sigm(zf), gg = tanh_fast(zg), og = sigm(zo);
      c_state = fg * c_state + ig * gg;
      float hval = og * tanh_fast(c_state);

      unsigned hword = ((unsigned)f2bf(hval) << 16) | (unsigned)((t + 1) & 0xFFFF);
      __hip_atomic_store(hb + (size_t)((t + 1) & 1) * (BATCH * HID) +
                             (size_t)(g0 + row) * HID + hcol,
                         hword, __ATOMIC_RELAXED, __HIP_MEMORY_SCOPE_AGENT);

      // logit partials AFTER h store (ack latency off critical path)
      float p0 = hval * wo.x, p1 = hval * wo.y;
      p0 += __shfl_xor(p0, 16); p1 += __shfl_xor(p1, 16);
      p0 += __shfl_xor(p0, 8);  p1 += __shfl_xor(p1, 8);
      p0 += __shfl_xor(p0, 4);  p1 += __shfl_xor(p1, 4);
      p0 += __shfl_xor(p0, 2);  p1 += __shfl_xor(p1, 2);
      p0 += __shfl_xor(p0, 1);  p1 += __shfl_xor(p1, 1);
      if (col == 0) {
        float* po = out + ((size_t)(g0 + row) * TLEN + t) * 2;
        atomicAdd(po + 0, p0);
        atomicAdd(po + 1, p1);
      }
    }
  }
}

// ---- logits -> softmax probs + NLL ----
__global__ void k_out2(float* __restrict__ out, const float* __restrict__ bo,
                       const int* __restrict__ labels, float* __restrict__ acc) {
  __shared__ float sred[4];
  int i = blockIdx.x * 256 + threadIdx.x;   // 0..65535 = b*T + t
  float l0 = out[(size_t)i * 2 + 0] + bo[0];
  float l1 = out[(size_t)i * 2 + 1] + bo[1];
  float mx = fmaxf(l0, l1);
  float e0 = __expf(l0 - mx), e1 = __expf(l1 - mx);
  float s = e0 + e1, inv = 1.0f / s;
  out[(size_t)i * 2 + 0] = e0 * inv;
  out[(size_t)i * 2 + 1] = e1 * inv;
  int lab = labels[i];
  float nll = __logf(s) - ((lab ? l1 : l0) - mx);
#pragma unroll
  for (int off = 32; off >= 1; off >>= 1) nll += __shfl_xor(nll, off);
  if ((threadIdx.x & 63) == 0) sred[threadIdx.x >> 6] = nll;
  __syncthreads();
  if (threadIdx.x == 0)
    atomicAdd(acc, sred[0] + sred[1] + sred[2] + sred[3]);
}

__global__ void k_fin(const float* __restrict__ acc, float* __restrict__ out) {
  out[BATCH * TLEN * 2] = acc[0] * (1.0f / (float)(BATCH * TLEN));
}

extern "C" void kernel_launch(void* const* d_in, const int* in_sizes, int n_in,
                              void* d_out, int out_size, void* d_ws, size_t ws_size,
                              hipStream_t stream) {
  const float* x      = (const float*)d_in[0];
  const int*   labels = (const int*)d_in[1];
  const float* Wx     = (const float*)d_in[2];
  const float* Wh     = (const float*)d_in[3];
  const float* b      = (const float*)d_in[4];
  const float* Wo     = (const float*)d_in[5];
  const float* bo     = (const float*)d_in[6];
  float* out = (float*)d_out;
  char* ws = (char*)d_ws;

  unsigned short* Wt  = (unsigned short*)(ws + OFF_WT);
  unsigned short* xbf = (unsigned short*)(ws + OFF_XBF);
  unsigned*       hb  = (unsigned*)(ws + OFF_HB);
  float*          acc = (float*)(ws + OFF_ACC);

  // hb zero => h_0 = 0 with tag 0 (self-validating); acc zero; out zero
  hipMemsetAsync(ws + OFF_HB, 0, ZERO_LEN, stream);
  hipMemsetAsync(d_out, 0, (size_t)BATCH * TLEN * 2 * sizeof(float), stream);
  k_convx<<<8192, 256, 0, stream>>>((const float4*)x, (ushort4*)xbf);
  k_tw<<<640, 256, 0, stream>>>(Wx, Wh, Wt);
  k_lstm<<<128, 512, 0, stream>>>(xbf, Wt, b, Wo, hb, out);
  k_out2<<<256, 256, 0, stream>>>(out, bo, labels, acc);
  k_fin<<<1, 1, 0, stream>>>(acc, out);
}

// Round 7
// 2785.163 us; speedup vs baseline: 3.1576x; 1.1850x over previous
//
#include <hip/hip_runtime.h>
#include <stdint.h>

#define TLEN 1024
#define BATCH 64
#define DIMX 128
#define HID 512

typedef __attribute__((ext_vector_type(8))) short short8;
typedef __attribute__((ext_vector_type(4))) float f32x4;
typedef __attribute__((ext_vector_type(4))) unsigned u32x4;

// ---- workspace layout (bytes) ----
#define OFF_WT   0u           // Wt: [2048][640] bf16 = 2,621,440
#define OFF_XBF  2621440u     // xbf: [64][1024][128] bf16 = 16,777,216
#define OFF_HB   19398656u    // hb: [2][64][512] u32 (tagged bf16) = 262,144
#define OFF_ACC  19660800u    // acc: 64
#define ZERO_LEN (262144u + 64u)

__device__ __forceinline__ unsigned short f2bf(float f) {
  unsigned u = __float_as_uint(f);
  u += 0x7fffu + ((u >> 16) & 1u);
  return (unsigned short)(u >> 16);
}
__device__ __forceinline__ float sigm(float x) { return 1.0f / (1.0f + __expf(-x)); }
__device__ __forceinline__ float tanh_fast(float x) {
  float a = fabsf(x);
  float e = __expf(2.0f * a);
  float t = 1.0f - 2.0f / (e + 1.0f);
  return copysignf(t, x);
}

// ---- x fp32 -> bf16, coalesced ----
__global__ void k_convx(const float4* __restrict__ x4, ushort4* __restrict__ o4) {
  int i = blockIdx.x * 256 + threadIdx.x;
  float4 v = x4[i];
  ushort4 o;
  o.x = f2bf(v.x); o.y = f2bf(v.y); o.z = f2bf(v.z); o.w = f2bf(v.w);
  o4[i] = o;
}

// ---- build Wt[col 0..2047][k 0..639] bf16 = concat(Wx;Wh)^T (proven) ----
__global__ void k_tw(const float* __restrict__ Wx, const float* __restrict__ Wh,
                     unsigned short* __restrict__ Wt) {
  __shared__ float tile[32][65];
  int bk = blockIdx.x;
  int k0 = (bk / 64) * 64;
  int c0 = (bk % 64) * 32;
  int tid = threadIdx.x;
  const float* src = (k0 < 128) ? (Wx + (size_t)k0 * 2048)
                                : (Wh + (size_t)(k0 - 128) * 2048);
#pragma unroll
  for (int p = 0; p < 8; ++p) {
    int i = p * 256 + tid;
    int kk = i >> 5, cc = i & 31;
    tile[cc][kk] = src[(size_t)kk * 2048 + (c0 + cc)];
  }
  __syncthreads();
  int cc = tid >> 3, ch = tid & 7;
  unsigned short tmp[8];
#pragma unroll
  for (int j = 0; j < 8; ++j) tmp[j] = f2bf(tile[cc][ch * 8 + j]);
  uint4 o;
  o.x = (unsigned)tmp[0] | ((unsigned)tmp[1] << 16);
  o.y = (unsigned)tmp[2] | ((unsigned)tmp[3] << 16);
  o.z = (unsigned)tmp[4] | ((unsigned)tmp[5] << 16);
  o.w = (unsigned)tmp[6] | ((unsigned)tmp[7] << 16);
  *(uint4*)(Wt + (size_t)(c0 + cc) * 640 + k0 + ch * 8) = o;
}

// ---- recurrence: 128 WGs = 8 groups(8 rows) x 16 WGs(512thr = 8 waves) ----
// R6 + half-window polls with LDS sibling exchange + dwordx4 h-stores.
__global__ __launch_bounds__(512, 1) void k_lstm(
    const unsigned short* __restrict__ xbf,   // [B][T][D] bf16
    const unsigned short* __restrict__ Wt,    // [4H][640] bf16 (B^T layout)
    const float* __restrict__ bias,           // [4H]
    const float* __restrict__ Wo,             // [H][2]
    unsigned* __restrict__ hb,                // [2][B][H] tagged u32
    float* __restrict__ out)                  // [B][T][2] logits via atomicAdd
{
  __shared__ float red[2][4][4][8][32];    // 32 KB z-partial staging
  __shared__ short8 xch[2][4][2][2][64];   // 32 KB half-window exchange
  __shared__ unsigned xflag[2][4][2];

  const int tid  = threadIdx.x;
  const int w    = tid >> 6;      // wave 0..7
  const int kw   = w & 3;         // K-split: x chunk kw, h window kw*128..+127
  const int cg   = w >> 2;        // gate-pair id AND poll-half id
  const int lane = tid & 63;
  const int q    = lane >> 4;
  const int m    = lane & 15;
  const int grp  = blockIdx.x & 7;
  const int hj   = blockIdx.x >> 3;  // producer slice 0..15 (cols hj*32..+31)
  const int g0   = grp * 8;

  if (tid < 16) xflag[tid >> 3][(tid >> 1) & 3][tid & 1] = 0;

  // ---- pin weight slice in registers (balanced-K mapping, as R6) ----
  short8 Bf[5][4];
#pragma unroll
  for (int cc = 0; cc < 5; ++cc) {
#pragma unroll
    for (int j = 0; j < 4; ++j) {
      int gate = cg * 2 + (j >> 1);
      int col = gate * HID + hj * 32 + (j & 1) * 16 + m;
      int k = (cc == 0) ? (kw * 32 + q * 8)
                        : (128 + kw * 128 + (cc - 1) * 32 + q * 8);
      Bf[cc][j] = *(const short8*)(Wt + (size_t)col * 640 + k);
    }
  }

  // gate duty: wave w owns row w; lanes 0..31 own cols
  const int col  = lane & 31;
  const int hcol = hj * 32 + col;
  float c_state = 0.0f;
  const float b_i = bias[0 * HID + hcol];
  const float b_f = bias[1 * HID + hcol];
  const float b_g = bias[2 * HID + hcol];
  const float b_o = bias[3 * HID + hcol];
  const float2 wo = ((const float2*)Wo)[hcol];

  const int arow = (m < 8) ? m : 7;   // clamp pad rows (coalesced dup = free)
  const int ab = g0 + arow;

  __syncthreads();   // xflag init visible

#pragma unroll 1
  for (int t = 0; t < TLEN; ++t) {
    const unsigned* hin = hb + (size_t)(t & 1) * (BATCH * HID);
    const int buf = t & 1;

    // ---- x chunk (plain cached load) ----
    short8 a0 = *(const short8*)(xbf + ((size_t)ab * TLEN + t) * DIMX +
                                 kw * 32 + q * 8);

    // ---- own half-window: batched bypass poll, detect==data ----
    const unsigned* pb = hin + (size_t)ab * HID + kw * 128 + cg * 64 + q * 8;
    u32x4 r0, r1, r2, r3;
    {
      const unsigned tg = (unsigned)t & 0xFFFFu;
      int guard = 0;
      for (;;) {
        asm volatile(
            "global_load_dwordx4 %0, %4, off sc0 sc1\n\t"
            "global_load_dwordx4 %1, %4, off offset:16 sc0 sc1\n\t"
            "global_load_dwordx4 %2, %4, off offset:128 sc0 sc1\n\t"
            "global_load_dwordx4 %3, %4, off offset:144 sc0 sc1\n\t"
            "s_waitcnt vmcnt(0)"
            : "=v"(r0), "=v"(r1), "=v"(r2), "=v"(r3)
            : "v"(pb)
            : "memory");
        unsigned d = (r0[0] ^ tg) | (r0[1] ^ tg) | (r0[2] ^ tg) | (r0[3] ^ tg);
        d |= (r1[0] ^ tg) | (r1[1] ^ tg) | (r1[2] ^ tg) | (r1[3] ^ tg);
        d |= (r2[0] ^ tg) | (r2[1] ^ tg) | (r2[2] ^ tg) | (r2[3] ^ tg);
        d |= (r3[0] ^ tg) | (r3[1] ^ tg) | (r3[2] ^ tg) | (r3[3] ^ tg);
        bool bad = (d & 0xFFFFu) != 0u;
        if (__ballot(bad) == 0ull || ++guard > (1 << 20)) break;
      }
    }

    // ---- pack own half -> 2 frags ----
    short8 f0, f1;
    {
      union { short8 s; unsigned u[4]; } pk;
      pk.u[0] = (r0[0] >> 16) | (r0[1] & 0xFFFF0000u);
      pk.u[1] = (r0[2] >> 16) | (r0[3] & 0xFFFF0000u);
      pk.u[2] = (r1[0] >> 16) | (r1[1] & 0xFFFF0000u);
      pk.u[3] = (r1[2] >> 16) | (r1[3] & 0xFFFF0000u);
      f0 = pk.s;
      pk.u[0] = (r2[0] >> 16) | (r2[1] & 0xFFFF0000u);
      pk.u[1] = (r2[2] >> 16) | (r2[3] & 0xFFFF0000u);
      pk.u[2] = (r3[0] >> 16) | (r3[1] & 0xFFFF0000u);
      pk.u[3] = (r3[2] >> 16) | (r3[3] & 0xFFFF0000u);
      f1 = pk.s;
    }

    // ---- publish own half to sibling; fetch sibling half ----
    xch[buf][kw][cg][0][lane] = f0;
    xch[buf][kw][cg][1][lane] = f1;
    __hip_atomic_store(&xflag[buf][kw][cg], (unsigned)(t + 1),
                       __ATOMIC_RELEASE, __HIP_MEMORY_SCOPE_WORKGROUP);
    {
      int guard = 0;
      while (__hip_atomic_load(&xflag[buf][kw][cg ^ 1], __ATOMIC_ACQUIRE,
                               __HIP_MEMORY_SCOPE_WORKGROUP) < (unsigned)(t + 1)) {
        if (++guard > (1 << 22)) break;
      }
    }
    short8 s0 = xch[buf][kw][cg ^ 1][0][lane];
    short8 s1 = xch[buf][kw][cg ^ 1][1][lane];

    // a[1..4]: words kw*128+[0,32,64,96)+...; own half cg=0 -> a1,a2; cg=1 -> a3,a4
    short8 a1 = cg ? s0 : f0;
    short8 a2 = cg ? s1 : f1;
    short8 a3 = cg ? f0 : s0;
    short8 a4 = cg ? f1 : s1;

    // ---- MFMA: z partials for this wave's K-slice, gate pair ----
    f32x4 z0 = {0,0,0,0}, z1 = {0,0,0,0}, z2 = {0,0,0,0}, z3 = {0,0,0,0};
    z0 = __builtin_amdgcn_mfma_f32_16x16x32_bf16(a0, Bf[0][0], z0, 0, 0, 0);
    z1 = __builtin_amdgcn_mfma_f32_16x16x32_bf16(a0, Bf[0][1], z1, 0, 0, 0);
    z2 = __builtin_amdgcn_mfma_f32_16x16x32_bf16(a0, Bf[0][2], z2, 0, 0, 0);
    z3 = __builtin_amdgcn_mfma_f32_16x16x32_bf16(a0, Bf[0][3], z3, 0, 0, 0);
    z0 = __builtin_amdgcn_mfma_f32_16x16x32_bf16(a1, Bf[1][0], z0, 0, 0, 0);
    z1 = __builtin_amdgcn_mfma_f32_16x16x32_bf16(a1, Bf[1][1], z1, 0, 0, 0);
    z2 = __builtin_amdgcn_mfma_f32_16x16x32_bf16(a1, Bf[1][2], z2, 0, 0, 0);
    z3 = __builtin_amdgcn_mfma_f32_16x16x32_bf16(a1, Bf[1][3], z3, 0, 0, 0);
    z0 = __builtin_amdgcn_mfma_f32_16x16x32_bf16(a2, Bf[2][0], z0, 0, 0, 0);
    z1 = __builtin_amdgcn_mfma_f32_16x16x32_bf16(a2, Bf[2][1], z1, 0, 0, 0);
    z2 = __builtin_amdgcn_mfma_f32_16x16x32_bf16(a2, Bf[2][2], z2, 0, 0, 0);
    z3 = __builtin_amdgcn_mfma_f32_16x16x32_bf16(a2, Bf[2][3], z3, 0, 0, 0);
    z0 = __builtin_amdgcn_mfma_f32_16x16x32_bf16(a3, Bf[3][0], z0, 0, 0, 0);
    z1 = __builtin_amdgcn_mfma_f32_16x16x32_bf16(a3, Bf[3][1], z1, 0, 0, 0);
    z2 = __builtin_amdgcn_mfma_f32_16x16x32_bf16(a3, Bf[3][2], z2, 0, 0, 0);
    z3 = __builtin_amdgcn_mfma_f32_16x16x32_bf16(a3, Bf[3][3], z3, 0, 0, 0);
    z0 = __builtin_amdgcn_mfma_f32_16x16x32_bf16(a4, Bf[4][0], z0, 0, 0, 0);
    z1 = __builtin_amdgcn_mfma_f32_16x16x32_bf16(a4, Bf[4][1], z1, 0, 0, 0);
    z2 = __builtin_amdgcn_mfma_f32_16x16x32_bf16(a4, Bf[4][2], z2, 0, 0, 0);
    z3 = __builtin_amdgcn_mfma_f32_16x16x32_bf16(a4, Bf[4][3], z3, 0, 0, 0);

    // ---- stage partials (valid rows in quads 0,1), double-buffered ----
    if (q < 2) {
#pragma unroll
      for (int r = 0; r < 4; ++r) {
        int rw = q * 4 + r;
        red[buf][kw][cg * 2 + 0][rw][0 * 16 + m] = z0[r];
        red[buf][kw][cg * 2 + 0][rw][1 * 16 + m] = z1[r];
        red[buf][kw][cg * 2 + 1][rw][0 * 16 + m] = z2[r];
        red[buf][kw][cg * 2 + 1][rw][1 * 16 + m] = z3[r];
      }
    }
    __syncthreads();   // the only WG rendezvous per step

    // ---- gates: wave w owns row w; lanes 0..31 own cols ----
    if (lane < 32) {
      float zi = b_i + red[buf][0][0][w][col] + red[buf][1][0][w][col]
                     + red[buf][2][0][w][col] + red[buf][3][0][w][col];
      float zf = b_f + red[buf][0][1][w][col] + red[buf][1][1][w][col]
                     + red[buf][2][1][w][col] + red[buf][3][1][w][col];
      float zg = b_g + red[buf][0][2][w][col] + red[buf][1][2][w][col]
                     + red[buf][2][2][w][col] + red[buf][3][2][w][col];
      float zo = b_o + red[buf][0][3][w][col] + red[buf][1][3][w][col]
                     + red[buf][2][3][w][col] + red[buf][3][3][w][col];
      float ig = sigm(zi), fg = sigm(zf), gg = tanh_fast(zg), og = sigm(zo);
      c_state = fg * c_state + ig * gg;
      float hval = og * tanh_fast(c_state);

      unsigned hword = ((unsigned)f2bf(hval) << 16) | (unsigned)((t + 1) & 0xFFFF);
      // gather 4 cols -> one dwordx4 store (write-through LLC)
      int base = lane & ~3;
      unsigned w0 = __shfl(hword, base + 0);
      unsigned w1 = __shfl(hword, base + 1);
      unsigned w2 = __shfl(hword, base + 2);
      unsigned w3 = __shfl(hword, base + 3);
      if ((lane & 3) == 0) {
        u32x4 v4 = {w0, w1, w2, w3};
        unsigned* dst = hb + (size_t)((t + 1) & 1) * (BATCH * HID) +
                        (size_t)(g0 + w) * HID + hcol;
        asm volatile("global_store_dwordx4 %0, %1, off sc0 sc1"
                     :: "v"(dst), "v"(v4) : "memory");
      }

      // logit partials (fire-and-forget atomics)
      float p0 = hval * wo.x, p1 = hval * wo.y;
      p0 += __shfl_xor(p0, 16); p1 += __shfl_xor(p1, 16);
      p0 += __shfl_xor(p0, 8);  p1 += __shfl_xor(p1, 8);
      p0 += __shfl_xor(p0, 4);  p1 += __shfl_xor(p1, 4);
      p0 += __shfl_xor(p0, 2);  p1 += __shfl_xor(p1, 2);
      p0 += __shfl_xor(p0, 1);  p1 += __shfl_xor(p1, 1);
      if (lane == 0) {
        float* po = out + ((size_t)(g0 + w) * TLEN + t) * 2;
        atomicAdd(po + 0, p0);
        atomicAdd(po + 1, p1);
      }
    }
  }
}

// ---- logits -> softmax probs + NLL ----
__global__ void k_out2(float* __restrict__ out, const float* __restrict__ bo,
                       const int* __restrict__ labels, float* __restrict__ acc) {
  __shared__ float sred[4];
  int i = blockIdx.x * 256 + threadIdx.x;   // 0..65535 = b*T + t
  float l0 = out[(size_t)i * 2 + 0] + bo[0];
  float l1 = out[(size_t)i * 2 + 1] + bo[1];
  float mx = fmaxf(l0, l1);
  float e0 = __expf(l0 - mx), e1 = __expf(l1 - mx);
  float s = e0 + e1, inv = 1.0f / s;
  out[(size_t)i * 2 + 0] = e0 * inv;
  out[(size_t)i * 2 + 1] = e1 * inv;
  int lab = labels[i];
  float nll = __logf(s) - ((lab ? l1 : l0) - mx);
#pragma unroll
  for (int off = 32; off >= 1; off >>= 1) nll += __shfl_xor(nll, off);
  if ((threadIdx.x & 63) == 0) sred[threadIdx.x >> 6] = nll;
  __syncthreads();
  if (threadIdx.x == 0)
    atomicAdd(acc, sred[0] + sred[1] + sred[2] + sred[3]);
}

__global__ void k_fin(const float* __restrict__ acc, float* __restrict__ out) {
  out[BATCH * TLEN * 2] = acc[0] * (1.0f / (float)(BATCH * TLEN));
}

extern "C" void kernel_launch(void* const* d_in, const int* in_sizes, int n_in,
                              void* d_out, int out_size, void* d_ws, size_t ws_size,
                              hipStream_t stream) {
  const float* x      = (const float*)d_in[0];
  const int*   labels = (const int*)d_in[1];
  const float* Wx     = (const float*)d_in[2];
  const float* Wh     = (const float*)d_in[3];
  const float* b      = (const float*)d_in[4];
  const float* Wo     = (const float*)d_in[5];
  const float* bo     = (const float*)d_in[6];
  float* out = (float*)d_out;
  char* ws = (char*)d_ws;

  unsigned short* Wt  = (unsigned short*)(ws + OFF_WT);
  unsigned short* xbf = (unsigned short*)(ws + OFF_XBF);
  unsigned*       hb  = (unsigned*)(ws + OFF_HB);
  float*          acc = (float*)(ws + OFF_ACC);

  // hb zero => h_0 = 0 with tag 0 (self-validating); acc zero; out zero
  hipMemsetAsync(ws + OFF_HB, 0, ZERO_LEN, stream);
  hipMemsetAsync(d_out, 0, (size_t)BATCH * TLEN * 2 * sizeof(float), stream);
  k_convx<<<8192, 256, 0, stream>>>((const float4*)x, (ushort4*)xbf);
  k_tw<<<640, 256, 0, stream>>>(Wx, Wh, Wt);
  k_lstm<<<128, 512, 0, stream>>>(xbf, Wt, b, Wo, hb, out);
  k_out2<<<256, 256, 0, stream>>>(out, bo, labels, acc);
  k_fin<<<1, 1, 0, stream>>>(acc, out);
}